// Round 5
// baseline (529.553 us; speedup 1.0000x reference)
//
#include <hip/hip_runtime.h>

// B=16384, T=56, F=56, H=20, 3H=60, FC1=128, NC=2
// R8: fused kernel, latency fixes over R7:
//  - depth-2 x prefetch: 4 LDS row-buffers, issue row t+2 each iter, wait
//    vmcnt(2) (~1000 cycles of cover vs ~900-cycle HBM latency).
//  - layer-0 h-dot (SGPR hA2, x-independent) moved BEFORE the vmcnt wait.
//  - VGPR-side packed math via __builtin_elementwise_fma on f32x2 with
//    shufflevector extraction from f32x4 LDS reads (no asm operand copies).
//    asm pkfma_s kept only for the SGPR-operand h-recurrence dots.

#define Bsz  16384
#define Tt   56
#define Ff   56
#define Hh   20
#define Gg   60
#define FC1n 128
#define THn  1120  // T*H

// ws float layout: [0..2239] weff, [2240..2241] beff
#define WS_WEFF 0
#define WS_BEFF 2240

typedef __attribute__((address_space(1))) const unsigned char gas_uchar;
typedef __attribute__((address_space(3))) unsigned char las_uchar;
typedef __attribute__((ext_vector_type(2))) float f32x2;
typedef __attribute__((ext_vector_type(4))) float f32x4;

__device__ __forceinline__ float rdlane(float v, int l) {
  return __uint_as_float(__builtin_amdgcn_readlane(__float_as_uint(v), l));
}
__device__ __forceinline__ float bperm(int addr, float v) {
  return __uint_as_float(__builtin_amdgcn_ds_bpermute(addr, __float_as_uint(v)));
}
__device__ __forceinline__ float fast_rcp(float x) { return __builtin_amdgcn_rcpf(x); }
__device__ __forceinline__ float sigmoid_fast(float x) { return fast_rcp(1.0f + __expf(-x)); }
__device__ __forceinline__ float tanh_fast(float x) { return 1.0f - 2.0f * fast_rcp(1.0f + __expf(2.0f * x)); }

__device__ __forceinline__ f32x2 mk2(float a, float b) { f32x2 r; r.x = a; r.y = b; return r; }

// packed fma via builtin (compiler-scheduled, subreg-tied operands)
__device__ __forceinline__ f32x2 vfma2(f32x2 a, f32x2 b, f32x2 c) {
  return __builtin_elementwise_fma(a, b, c);
}
#define LO2(q) __builtin_shufflevector((q), (q), 0, 1)
#define HI2(q) __builtin_shufflevector((q), (q), 2, 3)

// packed fma, SGPR-pair first operand (persisted h broadcasts)
__device__ __forceinline__ f32x2 pkfma_s(f32x2 hs, f32x2 wv, f32x2 c) {
  f32x2 d;
  asm("v_pk_fma_f32 %0, %1, %2, %3" : "=v"(d) : "s"(hs), "v"(wv), "v"(c));
  return d;
}

__device__ __forceinline__ void gru_cell(float xg, float hg, int addrR, int addrZ, float& hm) {
  float sg = sigmoid_fast(xg + hg);     // r on lanes 0..19, z on 20..39
  float rr = bperm(addrR, sg);
  float nn = tanh_fast(fmaf(rr, hg, xg));
  float zz = bperm(addrZ, sg);
  hm = fmaf(zz, hm - nn, nn);           // n + z*(h-n)
}

// ---------------- prep: W_eff = Wfc2 @ Wfc1 (folded FC), b_eff ----------------
__global__ void prep_all(const float* __restrict__ Wfc1, const float* __restrict__ bfc1,
                         const float* __restrict__ Wfc2, const float* __restrict__ bfc2,
                         float* __restrict__ ws) {
  int i = blockIdx.x * blockDim.x + threadIdx.x;
  if (i < THn) {
    float s0a = 0.f, s1a = 0.f, s0b = 0.f, s1b = 0.f;
    float s0c = 0.f, s1c = 0.f, s0d = 0.f, s1d = 0.f;
#pragma unroll 4
    for (int j = 0; j < FC1n; j += 4) {
      float wa = Wfc1[(j + 0) * THn + i];
      float wb = Wfc1[(j + 1) * THn + i];
      float wc = Wfc1[(j + 2) * THn + i];
      float wd = Wfc1[(j + 3) * THn + i];
      s0a = fmaf(wa, Wfc2[j + 0], s0a); s1a = fmaf(wa, Wfc2[FC1n + j + 0], s1a);
      s0b = fmaf(wb, Wfc2[j + 1], s0b); s1b = fmaf(wb, Wfc2[FC1n + j + 1], s1b);
      s0c = fmaf(wc, Wfc2[j + 2], s0c); s1c = fmaf(wc, Wfc2[FC1n + j + 2], s1c);
      s0d = fmaf(wd, Wfc2[j + 3], s0d); s1d = fmaf(wd, Wfc2[FC1n + j + 3], s1d);
    }
    ws[WS_WEFF + i * 2 + 0] = (s0a + s0b) + (s0c + s0d);
    ws[WS_WEFF + i * 2 + 1] = (s1a + s1b) + (s1c + s1d);
  } else if (i < THn + 2) {
    int c = i - THn;
    float s = bfc2[c];
    for (int j = 0; j < FC1n; ++j) s = fmaf(bfc1[j], Wfc2[c * FC1n + j], s);
    ws[WS_BEFF + c] = s;
  }
}

// ---------------- fused scan: 2 elems/wave, in-loop xproj, depth-2 pipe ----------------
__global__ __launch_bounds__(256, 3) void gru_fused(
    const float* __restrict__ x,
    const float* __restrict__ Wih0, const float* __restrict__ bih0,
    const float* __restrict__ Whh0, const float* __restrict__ bhh0,
    const float* __restrict__ Wih1, const float* __restrict__ bih1,
    const float* __restrict__ Whh1, const float* __restrict__ bhh1,
    const float* __restrict__ ws, float* __restrict__ y) {
  __shared__ float weff[2 * THn + 2];
  __shared__ __align__(16) float xstage[4][4][2 * Ff];  // [wave][buf][e0 row | e1 row]
  __shared__ __align__(16) float hstage[4][2][64];      // [wave][e][lane]
  for (int idx = threadIdx.x; idx < 2 * THn + 2; idx += 256) weff[idx] = ws[idx];
  __syncthreads();

  const int lane = threadIdx.x & 63;
  const int wv = threadIdx.x >> 6;
  const int b0 = (blockIdx.x * 4 + wv) * 2;  // elems b0, b0+1
  const int g = (lane < Gg) ? lane : 0;

  // per-lane weight rows as f32x2 pairs over input index
  f32x2 wih0p[28], whh0p[10], wih1p[10], whh1p[10];
#pragma unroll
  for (int i = 0; i < 28; ++i) wih0p[i] = *(const f32x2*)&Wih0[g * Ff + 2 * i];
#pragma unroll
  for (int i = 0; i < 10; ++i) whh0p[i] = *(const f32x2*)&Whh0[g * Hh + 2 * i];
#pragma unroll
  for (int i = 0; i < 10; ++i) wih1p[i] = *(const f32x2*)&Wih1[g * Hh + 2 * i];
#pragma unroll
  for (int i = 0; i < 10; ++i) whh1p[i] = *(const f32x2*)&Whh1[g * Hh + 2 * i];

  const f32x2 cbi0 = mk2(bih0[g], 0.f);
  const f32x2 cb0  = mk2(bhh0[g], 0.f);
  const f32x2 cb1i = mk2(bih1[g], 0.f);
  const f32x2 cb1h = mk2(bhh1[g], 0.f);
  const f32x2 zz2  = mk2(0.f, 0.f);

  float hmA[2] = {0.f, 0.f};
  float hmB[2] = {0.f, 0.f};
  f32x2 hA2[2][10];  // persisted SGPR-pair broadcasts of hmA
#pragma unroll
  for (int e = 0; e < 2; ++e)
#pragma unroll
    for (int i = 0; i < 10; ++i) hA2[e][i] = zz2;

  hstage[wv][0][lane] = 0.f;
  hstage[wv][1][lane] = 0.f;

  float ya[2] = {0.f, 0.f};
  float yb[2] = {0.f, 0.f};

  const int addrR = ((lane >= 40) ? (lane - 40) : lane) * 4;
  const int addrZ = ((lane >= 40) ? (lane - 20) : lane) * 4;
  const int jm = (lane >= 40 && lane < Gg) ? lane - 40 : 0;

  // per-lane x source: lanes 0..13 cover elem b0's row (16B chunks),
  // lanes 14..27 cover elem b0+1's row. LDS dest is base + lane*16 (HW rule),
  // so [e0 row | e1 row] lands contiguously.
  const int le = (lane >= 14) ? 1 : 0;
  const int lc = lane - le * 14;
  const float* xsrc = x + (size_t)(b0 + le) * (Tt * Ff) + lc * 4;

  // prologue: rows 0 and 1 in flight
  if (lane < 28) {
    __builtin_amdgcn_global_load_lds((gas_uchar*)xsrc,
                                     (las_uchar*)&xstage[wv][0][0], 16, 0, 0);
    __builtin_amdgcn_global_load_lds((gas_uchar*)(xsrc + Ff),
                                     (las_uchar*)&xstage[wv][1][0], 16, 0, 0);
  }

#pragma unroll 1
  for (int t = 0; t < Tt; ++t) {
    // issue row t+2 (clamped re-read near the tail keeps vmcnt accounting uniform)
    const float* nxt = xsrc + ((t + 2 < Tt) ? 2 * Ff : (size_t)(Tt - 1 - t) * Ff);
    if (lane < 28) {
      __builtin_amdgcn_global_load_lds((gas_uchar*)nxt,
                                       (las_uchar*)&xstage[wv][(t + 2) & 3][0], 16, 0, 0);
    }

    // ---- layer-0 h-dot first (SGPR hA2, no x dependency) ----
    float hg0[2];
#pragma unroll
    for (int e = 0; e < 2; ++e) {
      f32x2 c = pkfma_s(hA2[e][0], whh0p[0], cb0);
      f32x2 d = pkfma_s(hA2[e][1], whh0p[1], zz2);
#pragma unroll
      for (int i = 2; i < 10; i += 2) {
        c = pkfma_s(hA2[e][i], whh0p[i], c);
        d = pkfma_s(hA2[e][i + 1], whh0p[i + 1], d);
      }
      f32x2 sh = c + d;
      hg0[e] = sh.x + sh.y;
    }

    asm volatile("s_waitcnt vmcnt(2)" ::: "memory");

    // ---- layer 0: ig = Wih0 . x(t) + bi0 (uniform LDS broadcast) ----
#pragma unroll
    for (int e = 0; e < 2; ++e) {
      const f32x4* xb = (const f32x4*)&xstage[wv][t & 3][e * Ff];  // uniform
      f32x4 q = xb[0];
      f32x2 a = vfma2(LO2(q), wih0p[0], cbi0);
      f32x2 b = vfma2(HI2(q), wih0p[1], zz2);
#pragma unroll
      for (int i = 1; i < 14; ++i) {
        q = xb[i];
        a = vfma2(LO2(q), wih0p[2 * i], a);
        b = vfma2(HI2(q), wih0p[2 * i + 1], b);
      }
      f32x2 sx = a + b;
      float xg = sx.x + sx.y;
      gru_cell(xg, hg0[e], addrR, addrZ, hmA[e]);
      // refresh broadcasts of the NEW hmA into SGPR pairs (serves layer-1 ih
      // at t and layer-0 hh at t+1)
#pragma unroll
      for (int i = 0; i < 10; ++i)
        hA2[e][i] = mk2(rdlane(hmA[e], 40 + 2 * i), rdlane(hmA[e], 41 + 2 * i));
    }

    // ---- layer 1: ig = Wih1 . h1(t) (SGPR), hg = Whh1 . h2(t-1) (LDS quads) ----
#pragma unroll
    for (int e = 0; e < 2; ++e) {
      f32x2 ai = pkfma_s(hA2[e][0], wih1p[0], cb1i);
      f32x2 bi = pkfma_s(hA2[e][1], wih1p[1], zz2);
#pragma unroll
      for (int i = 2; i < 10; i += 2) {
        ai = pkfma_s(hA2[e][i], wih1p[i], ai);
        bi = pkfma_s(hA2[e][i + 1], wih1p[i + 1], bi);
      }
      const f32x4* hb = (const f32x4*)&hstage[wv][e][40];  // uniform -> broadcast
      f32x4 q0 = hb[0], q1 = hb[1], q2 = hb[2], q3 = hb[3], q4 = hb[4];
      f32x2 ah = vfma2(LO2(q0), whh1p[0], cb1h);
      f32x2 bh = vfma2(HI2(q0), whh1p[1], zz2);
      ah = vfma2(LO2(q1), whh1p[2], ah);
      bh = vfma2(HI2(q1), whh1p[3], bh);
      ah = vfma2(LO2(q2), whh1p[4], ah);
      bh = vfma2(HI2(q2), whh1p[5], bh);
      ah = vfma2(LO2(q3), whh1p[6], ah);
      bh = vfma2(HI2(q3), whh1p[7], bh);
      ah = vfma2(LO2(q4), whh1p[8], ah);
      bh = vfma2(HI2(q4), whh1p[9], bh);
      f32x2 si = ai + bi;
      float ig = si.x + si.y;
      f32x2 sh = ah + bh;
      float hg = sh.x + sh.y;
      gru_cell(ig, hg, addrR, addrZ, hmB[e]);
      hstage[wv][e][lane] = hmB[e];  // stage new h2 for t+1
    }

    // ---- FC accumulation (lane 40+j holds h2[t][j]) ----
    {
      float2 wv2 = *(const float2*)&weff[(t * Hh + jm) * 2];
#pragma unroll
      for (int e = 0; e < 2; ++e) {
        ya[e] = fmaf(hmB[e], wv2.x, ya[e]);
        yb[e] = fmaf(hmB[e], wv2.y, yb[e]);
      }
    }
    xsrc += Ff;
  }

  const bool active = (lane >= 40 && lane < Gg);
#pragma unroll
  for (int e = 0; e < 2; ++e) {
    if (!active) { ya[e] = 0.f; yb[e] = 0.f; }
  }
#pragma unroll
  for (int off2 = 32; off2 >= 1; off2 >>= 1) {
#pragma unroll
    for (int e = 0; e < 2; ++e) {
      ya[e] += __shfl_xor(ya[e], off2, 64);
      yb[e] += __shfl_xor(yb[e], off2, 64);
    }
  }
  if (lane == 0) {
    float be0 = weff[WS_BEFF], be1 = weff[WS_BEFF + 1];
    float4 o0 = make_float4(ya[0] + be0, yb[0] + be1, ya[1] + be0, yb[1] + be1);
    *(float4*)(y + (size_t)b0 * 2) = o0;
  }
}

extern "C" void kernel_launch(void* const* d_in, const int* in_sizes, int n_in,
                              void* d_out, int out_size, void* d_ws, size_t ws_size,
                              hipStream_t stream) {
  const float* x    = (const float*)d_in[0];
  const float* Wih0 = (const float*)d_in[1];
  const float* Whh0 = (const float*)d_in[2];
  const float* bih0 = (const float*)d_in[3];
  const float* bhh0 = (const float*)d_in[4];
  const float* Wih1 = (const float*)d_in[5];
  const float* Whh1 = (const float*)d_in[6];
  const float* bih1 = (const float*)d_in[7];
  const float* bhh1 = (const float*)d_in[8];
  const float* Wfc1 = (const float*)d_in[9];
  const float* bfc1 = (const float*)d_in[10];
  const float* Wfc2 = (const float*)d_in[11];
  const float* bfc2 = (const float*)d_in[12];
  float* ws = (float*)d_ws;
  float* y  = (float*)d_out;

  prep_all<<<5, 256, 0, stream>>>(Wfc1, bfc1, Wfc2, bfc2, ws);
  gru_fused<<<Bsz / 8, 256, 0, stream>>>(x, Wih0, bih0, Whh0, bhh0,
                                         Wih1, bih1, Whh1, bhh1, ws, y);
}